// Round 7
// baseline (441.712 us; speedup 1.0000x reference)
//
#include <hip/hip_runtime.h>
#include <math.h>

// Problem constants
//   B=128, S=256, DIM=512, D=128, K=16384, grid 16x16 -> conv out 8x8 -> N=B*64=8192
#define NROWS 8192
#define KCB   16384

using frag_ab = __attribute__((ext_vector_type(8))) short;   // 8 bf16 (4 VGPR)
using frag_cd = __attribute__((ext_vector_type(4))) float;   // 4 fp32 acc
using f32x4   = __attribute__((ext_vector_type(4))) float;
using f64x4   = __attribute__((ext_vector_type(4))) double;  // fp64 MFMA acc

__device__ inline unsigned short f2bf(float f) {             // RNE f32->bf16
    unsigned u = __float_as_uint(f);
    return (unsigned short)((u + 0x7FFFu + ((u >> 16) & 1u)) >> 16);
}

// Layout self-probe for v_mfma_f64_16x16x4 (HW-validated in round 3):
// decodes per-lane/slot (m,n) of the D fragment; returns ok.
__device__ inline int mfma_f64_probe(int pm[4], int pn[4], int kq) {
    f64x4 z; z[0] = 0.0; z[1] = 0.0; z[2] = 0.0; z[3] = 0.0;
    const double dl = (double)(threadIdx.x & 63);
    f64x4 d1 = __builtin_amdgcn_mfma_f64_16x16x4f64(dl, 1.0, z, 0, 0, 0);
    f64x4 d2 = __builtin_amdgcn_mfma_f64_16x16x4f64(1.0, dl, z, 0, 0, 0);
    const double pk = (double)(1 << (4 * kq));         // 16^kq
    f64x4 d3 = __builtin_amdgcn_mfma_f64_16x16x4f64(pk, dl, z, 0, 0, 0);
    int okl = 1;
    #pragma unroll
    for (int s = 0; s < 4; ++s) {
        double v1 = d1[s] - 96.0, v2 = d2[s] - 96.0;
        int i1 = (int)v1, i2 = (int)v2;
        okl &= (d1[s] == (double)(96 + i1)) & (i1 >= 0) & (i1 < 64) & ((i1 & 3) == 0);
        okl &= (d2[s] == (double)(96 + i2)) & (i2 >= 0) & (i2 < 64) & ((i2 & 3) == 0);
        pm[s] = i1 >> 2;
        pn[s] = i2 >> 2;
        okl &= (d3[s] == 4369.0 * (double)pn[s] + 205056.0);
    }
    return __all(okl);
}

// ---------------------------------------------------------------------------
// k_wt: transpose conv_w [co][ci][kh][kw] -> W2 [(kh*3+kw)][ci][co]  (f32)
__global__ __launch_bounds__(256) void k_wt(const float* __restrict__ cw,
                                            float* __restrict__ W2) {
    int gid = blockIdx.x * 256 + threadIdx.x;     // 147456 total
    if (gid >= 147456) return;
    int co = gid & 127;
    int ci = (gid >> 7) & 127;
    int kk = gid >> 14;                           // 0..8
    W2[gid] = cw[(size_t)co * 1152 + ci * 9 + kk];
}

// ---------------------------------------------------------------------------
// k_c2: c2f[k] = sum_d cb[k][d]^2 + 1024  (bias keeps k_dist scores positive
// so raw float bits are a monotone sort key; k_refine never reads c2f)
__global__ __launch_bounds__(256) void k_c2(const float* __restrict__ cb,
                                            float* __restrict__ c2f) {
    int k = blockIdx.x * 256 + threadIdx.x;
    const float* row = cb + (size_t)k * 128;
    double s = 0.0;
    #pragma unroll
    for (int d = 0; d < 128; d += 4) {
        float4 v = *(const float4*)(row + d);
        s += (double)v.x * v.x + (double)v.y * v.y
           + (double)v.z * v.z + (double)v.w * v.w;
    }
    c2f[k] = (float)s + 1024.0f;
}

// ---------------------------------------------------------------------------
// k_cbbf: convert codebook f32 -> bf16 rows [16384][128]
__global__ __launch_bounds__(256) void k_cbbf(const float* __restrict__ cb,
                                              unsigned short* __restrict__ Cbb) {
    int gid = blockIdx.x * 256 + threadIdx.x;     // x4 elements, 524288 total
    float4 v = ((const float4*)cb)[gid];
    ushort4 o;
    o.x = f2bf(v.x); o.y = f2bf(v.y); o.z = f2bf(v.z); o.w = f2bf(v.w);
    ((ushort4*)Cbb)[gid] = o;
}

// ---------------------------------------------------------------------------
// k_encode_gemm: H = (last - first) @ W_in, fp64 via v_mfma_f64_16x16x4.
// M=32768, N=128, K=512. Round-7: occupancy push. R4->R5 showed blocks/CU
// 2->4 moved MfmaUtil 44->53%; R6 dbuf was neutral (compiler/wave overlap
// already covers staging). So: BM=16, grid 2048 -> 8 blocks/CU (LDS 8.7 KiB,
// VGPR<=64 via launch_bounds(256,8)) = 8 waves/SIMD latency hiding.
// Wave w: 16 rows x cols [w*32, w*32+32) -> 2 f64x4 accs. B un-staged
// (W_in f32 from L2 + cvt, round-5 proven). MFMA k-quad sequence per output
// element identical to rounds 4-6 -> bit-identical H. Probe + fallback.
__global__ __launch_bounds__(256, 8) void k_encode_gemm(
    const float* __restrict__ last, const float* __restrict__ first,
    const float* __restrict__ W_in, double* __restrict__ H)
{
    __shared__ double As[64][17];    // [k][row] 8.7 KiB (pad 16->17)
    const int tid  = threadIdx.x;
    const int lane = tid & 63;
    const int w    = tid >> 6;
    const int row0 = blockIdx.x * 16;
    const int wn   = w * 32;
    const int lm   = lane & 15;
    const int kq   = lane >> 4;

    int pm[4], pn[4];
    const int ok = mfma_f64_probe(pm, pn, kq);
    if (!ok) {
        #pragma unroll
        for (int s = 0; s < 4; ++s) { pm[s] = 4 * kq + s; pn[s] = lm; }
    }

    f64x4 acc[2];
    #pragma unroll
    for (int j = 0; j < 2; ++j)
        #pragma unroll
        for (int q = 0; q < 4; ++q) acc[j][q] = 0.0;

    const int srow = tid >> 4;           // A-stage: row 0..15
    const int skb  = (tid & 15) * 4;     // A-stage: k base 0,4,...,60
    const float* lp0 = last  + (size_t)(row0 + srow) * 512 + skb;
    const float* fp0 = first + (size_t)(row0 + srow) * 512 + skb;

    for (int k0 = 0; k0 < 512; k0 += 64) {
        if (k0) __syncthreads();
        {   // stage A-diff (f64, transposed): 16 rows x 64 k
            const float4 l0 = *(const float4*)(lp0 + k0);
            const float4 f0 = *(const float4*)(fp0 + k0);
            As[skb + 0][srow] = (double)l0.x - (double)f0.x;
            As[skb + 1][srow] = (double)l0.y - (double)f0.y;
            As[skb + 2][srow] = (double)l0.z - (double)f0.z;
            As[skb + 3][srow] = (double)l0.w - (double)f0.w;
        }
        __syncthreads();
        if (ok) {
            #pragma unroll
            for (int kc = 0; kc < 16; ++kc) {
                const int kk = kc * 4 + kq;
                const float* wb = W_in + (size_t)(k0 + kk) * 128 + wn + lm;
                double a0 = As[kk][lm];
                double b0 = (double)wb[0];
                double b1 = (double)wb[16];
                acc[0] = __builtin_amdgcn_mfma_f64_16x16x4f64(a0, b0, acc[0], 0, 0, 0);
                acc[1] = __builtin_amdgcn_mfma_f64_16x16x4f64(a0, b1, acc[1], 0, 0, 0);
            }
        } else {
            #pragma unroll 4
            for (int k = 0; k < 64; ++k) {
                double b0 = (double)W_in[(size_t)(k0 + k) * 128 + wn + lm];
                double b1 = (double)W_in[(size_t)(k0 + k) * 128 + wn + 16 + lm];
                const double* ap = &As[k][4 * kq];
                #pragma unroll
                for (int s = 0; s < 4; ++s) {
                    double a = ap[s];
                    acc[0][s] = fma(a, b0, acc[0][s]);
                    acc[1][s] = fma(a, b1, acc[1][s]);
                }
            }
        }
    }
    #pragma unroll
    for (int j = 0; j < 2; ++j)
        #pragma unroll
        for (int s = 0; s < 4; ++s)
            H[(size_t)(row0 + pm[s]) * 128 + wn + 16 * j + pn[s]] = acc[j][s];
}

// ---------------------------------------------------------------------------
// k_conv: 3x3 stride-2 pad-1 conv (no bias; cancels), fp64 via MFMA.
// im2col GEMM: M=8192 out rows, N=128 co, K=9 taps x 128 ci.
// Block = 16 rows (batch b, oh pair {2j,2j+1}); input slice ih in
// [4j-1, 4j+3] -> Hs[5][16][128] f64 = 80 KiB exactly -> 2 blocks/CU.
// 4 waves x 32 co: per wave 1 m-frag x 2 n-frags; A from LDS (OOB taps
// masked by 0/1 multiplier), B = W2 f32 direct from L1/L2 + cvt.
// K-order tap-major (reassociation vs ci-major baseline: fp64 ulp, safe).
// Same probe + scalar fallback as encode.
__global__ __launch_bounds__(256) void k_conv(
    const double* __restrict__ H, const float* __restrict__ W2,
    double* __restrict__ X, unsigned short* __restrict__ Xb)
{
    __shared__ double Hs[5 * 2048];          // [ihr][iw][ci]  80 KiB exact
    const int tid  = threadIdx.x;
    const int lane = tid & 63;
    const int w    = tid >> 6;
    const int n0   = blockIdx.x * 16;        // 16 output rows
    const int b    = blockIdx.x >> 2;
    const int j    = blockIdx.x & 3;         // oh in {2j, 2j+1}
    const int ihbase = 4 * j - 1;
    const int wn   = w * 32;
    const int lm   = lane & 15;
    const int kq   = lane >> 4;

    int pm[4], pn[4];
    const int ok = mfma_f64_probe(pm, pn, kq);

    // stage 5 H rows (zero-fill ih=-1 for j==0)
    #pragma unroll
    for (int it = 0; it < 20; ++it) {
        int slot = it * 256 + tid;           // 5120 double2 slots
        int r = slot >> 10;                  // 0..4
        int rem = (slot & 1023) * 2;         // f64 offset within row
        int ih = ihbase + r;
        double2 v = (ih >= 0)
            ? *(const double2*)(H + (size_t)b * 32768 + (size_t)ih * 2048 + rem)
            : make_double2(0.0, 0.0);
        *(double2*)&Hs[r * 2048 + rem] = v;
    }
    __syncthreads();

    if (ok) {
        f64x4 acc0, acc1;
        #pragma unroll
        for (int q = 0; q < 4; ++q) { acc0[q] = 0.0; acc1[q] = 0.0; }
        const int ow = lm & 7, ohl = lm >> 3;
        #pragma unroll
        for (int kh = 0; kh < 3; ++kh) {
            #pragma unroll
            for (int kw = 0; kw < 3; ++kw) {
                const int tap = kh * 3 + kw;
                const int iw  = 2 * ow - 1 + kw;
                const int ihr = 2 * ohl + kh;
                const int valid = (iw >= 0) & (ihbase + ihr >= 0);
                const int aoff = valid ? (ihr * 2048 + iw * 128 + kq) : 0;
                const double msk = valid ? 1.0 : 0.0;
                const float* wbase = W2 + (size_t)(tap * 128 + kq) * 128 + wn + lm;
                #pragma unroll 4
                for (int ci0 = 0; ci0 < 128; ci0 += 4) {
                    double a  = Hs[aoff + ci0] * msk;
                    double b0 = (double)wbase[ci0 * 128];
                    double b1 = (double)wbase[ci0 * 128 + 16];
                    acc0 = __builtin_amdgcn_mfma_f64_16x16x4f64(a, b0, acc0, 0, 0, 0);
                    acc1 = __builtin_amdgcn_mfma_f64_16x16x4f64(a, b1, acc1, 0, 0, 0);
                }
            }
        }
        #pragma unroll
        for (int s = 0; s < 4; ++s) {
            size_t n = n0 + pm[s];
            int c0 = wn + pn[s];
            X [n * 128 + c0]      = acc0[s];
            Xb[n * 128 + c0]      = f2bf((float)acc0[s]);
            X [n * 128 + c0 + 16] = acc1[s];
            Xb[n * 128 + c0 + 16] = f2bf((float)acc1[s]);
        }
    } else {
        // scalar fallback (never runs on validated HW): 8 outputs/thread
        const int co   = wn + (lane & 31);
        const int half = lane >> 5;
        double facc[8];
        #pragma unroll
        for (int i = 0; i < 8; ++i) facc[i] = 0.0;
        for (int ci = 0; ci < 128; ++ci) {
            #pragma unroll
            for (int kh = 0; kh < 3; ++kh) {
                #pragma unroll
                for (int kw = 0; kw < 3; ++kw) {
                    double wv = (double)W2[(size_t)((kh * 3 + kw) * 128 + ci) * 128 + co];
                    #pragma unroll
                    for (int i = 0; i < 8; ++i) {
                        int m = half * 8 + i;
                        int iw = 2 * (m & 7) - 1 + kw;
                        int ihr = 2 * (m >> 3) + kh;
                        double hv = (iw >= 0 && ihbase + ihr >= 0)
                                  ? Hs[ihr * 2048 + iw * 128 + ci] : 0.0;
                        facc[i] = fma(hv, wv, facc[i]);
                    }
                }
            }
        }
        #pragma unroll
        for (int i = 0; i < 8; ++i) {
            size_t n = n0 + half * 8 + i;
            X [n * 128 + co] = facc[i];
            Xb[n * 128 + co] = f2bf((float)facc[i]);
        }
    }
}

// ---------------------------------------------------------------------------
// k_dist_mfma: bf16 MFMA candidate sweep. Block = 128 rows x 2048-code split;
// grid (64, 8) = 512 blocks (2/CU). Per chunk of 128 codes: 16x16x32 MFMA,
// codes as M, rows as N (D: col=lane&15=row, row=quad*4+reg=code).
// LDS exactly 64 KiB; 16B chunks XOR-swizzled (ch ^= row&15) -> conflict-free.
// Selection: score u = (||c||^2+1024) - 2 x.c > 0; sortable uint key =
// (bits(u) & ~0x7FF) | split-local code idx (11 bits); top-2 per (lane,row)
// class via min/max (no cndmask), then per-row top-2 of 16 via LDS.
// Coverage: bf16 noise sigma~0.05 + trunc <0.5 vs rank gaps ~7-20 -> safe;
// fp64 k_refine picks the exact argmin among the 16 candidates.
__global__ __launch_bounds__(256) void k_dist_mfma(
    const unsigned short* __restrict__ Xb, const unsigned short* __restrict__ Cbb,
    const float* __restrict__ c2f, int* __restrict__ cand)
{
    __shared__ __align__(16) unsigned short Xs[128 * 128];   // 32 KiB
    __shared__ __align__(16) unsigned short Cs[128 * 128];   // 32 KiB
    const int tid   = threadIdx.x;
    const int row0  = blockIdx.x * 128;
    const int split = blockIdx.y;
    const int lane  = tid & 63;
    const int w     = tid >> 6;
    const int quad  = lane >> 4;
    const int lm    = lane & 15;
    const int cw    = (w & 1) * 64;       // wave's code sub-tile
    const int rw    = (w >> 1) * 64;      // wave's row sub-tile

    #pragma unroll
    for (int it = 0; it < 8; ++it) {      // stage X tile once (swizzled)
        int flat = it * 256 + tid;
        int r = flat >> 4, ch = flat & 15;
        *(uint4*)&Xs[r * 128 + (((ch ^ r) & 15) << 3) + (ch & 16 ? 0 : 0)] =
            *(const uint4*)(Xb + (size_t)(row0 + r) * 128 + ch * 8);
    }

    unsigned k1[4], k2[4];
    #pragma unroll
    for (int j = 0; j < 4; ++j) { k1[j] = 0xFFFFFFFFu; k2[j] = 0xFFFFFFFFu; }

    for (int chunk = 0; chunk < 16; ++chunk) {
        const int kb = split * 2048 + chunk * 128;
        if (chunk) __syncthreads();
        #pragma unroll
        for (int it = 0; it < 8; ++it) {  // stage code chunk (swizzled)
            int flat = it * 256 + tid;
            int r = flat >> 4, ch = flat & 15;
            *(uint4*)&Cs[r * 128 + ((ch ^ (r & 15)) << 3)] =
                *(const uint4*)(Cbb + (size_t)(kb + r) * 128 + ch * 8);
        }
        __syncthreads();

        frag_cd acc[4][4];
        #pragma unroll
        for (int i = 0; i < 4; ++i)
            #pragma unroll
            for (int j = 0; j < 4; ++j)
                #pragma unroll
                for (int r = 0; r < 4; ++r) acc[i][j][r] = 0.f;

        #pragma unroll
        for (int kk = 0; kk < 4; ++kk) {
            const int chs = ((kk * 4 + quad) ^ lm) << 3;
            frag_ab a[4], b[4];
            #pragma unroll
            for (int i = 0; i < 4; ++i)
                a[i] = *(const frag_ab*)&Cs[(cw + i * 16 + lm) * 128 + chs];
            #pragma unroll
            for (int j = 0; j < 4; ++j)
                b[j] = *(const frag_ab*)&Xs[(rw + j * 16 + lm) * 128 + chs];
            #pragma unroll
            for (int i = 0; i < 4; ++i)
                #pragma unroll
                for (int j = 0; j < 4; ++j)
                    acc[i][j] = __builtin_amdgcn_mfma_f32_16x16x32_bf16(
                        a[i], b[j], acc[i][j], 0, 0, 0);
        }

        const int ib = chunk * 128 + cw + quad * 4;   // split-local idx base
        #pragma unroll
        for (int i = 0; i < 4; ++i) {
            f32x4 c2v = *(const f32x4*)(c2f + kb + cw + i * 16 + quad * 4);
            #pragma unroll
            for (int j = 0; j < 4; ++j) {
                #pragma unroll
                for (int r = 0; r < 4; ++r) {
                    float u = fmaf(-2.f, acc[i][j][r], c2v[r]);
                    unsigned key = (__float_as_uint(u) & 0xFFFFF800u)
                                 | (unsigned)(ib + i * 16 + r);
                    unsigned nk1 = min(key, k1[j]);
                    k2[j] = min(max(key, k1[j]), k2[j]);
                    k1[j] = nk1;
                }
            }
        }
    }

    // per-row reduce: 8 slots x 2 keys -> top-2 of the split
    __syncthreads();
    uint2* kred = (uint2*)Cs;             // [128 rows][8 slots]
    #pragma unroll
    for (int j = 0; j < 4; ++j)
        kred[(rw + j * 16 + lm) * 8 + (w & 1) * 4 + quad] = make_uint2(k1[j], k2[j]);
    __syncthreads();
    if (tid < 128) {
        unsigned b1 = 0xFFFFFFFFu, b2 = 0xFFFFFFFFu;
        for (int e = 0; e < 8; ++e) {
            uint2 kv = kred[tid * 8 + e];
            unsigned n1 = min(kv.x, b1); b2 = min(max(kv.x, b1), b2); b1 = n1;
            n1 = min(kv.y, b1);          b2 = min(max(kv.y, b1), b2); b1 = n1;
        }
        int base = split * 2048;
        int* o = cand + (size_t)(row0 + tid) * 16 + split * 2;
        o[0] = base + (int)(b1 & 0x7FFu);
        o[1] = base + (int)(b2 & 0x7FFu);
    }
}

// ---------------------------------------------------------------------------
// k_refine: fp64-exact argmin over 16 candidates; quantize; counts; indices.
__global__ __launch_bounds__(256) void k_refine(
    const double* __restrict__ X, const float* __restrict__ cb,
    const int* __restrict__ cand, const float* __restrict__ rnd,
    int* __restrict__ counts, float* __restrict__ quant,
    float* __restrict__ out_mi)
{
    const int wid  = threadIdx.x >> 6;
    const int lane = threadIdx.x & 63;
    const int row  = blockIdx.x * 4 + wid;
    const double x0 = X[(size_t)row * 128 + lane];
    const double x1 = X[(size_t)row * 128 + 64 + lane];
    double bestv = 1e300; int bestk = 0;
    for (int c = 0; c < 16; ++c) {
        int k = cand[(size_t)row * 16 + c] & (KCB - 1);   // defensive clamp
        double t0 = x0 - (double)cb[(size_t)k * 128 + lane];
        double t1 = x1 - (double)cb[(size_t)k * 128 + 64 + lane];
        double s = t0 * t0 + t1 * t1;
        #pragma unroll
        for (int off = 32; off > 0; off >>= 1) s += __shfl_xor(s, off, 64);
        if (s < bestv) { bestv = s; bestk = k; }
    }
    double r0 = (double)rnd[(size_t)row * 128 + lane];
    double r1 = (double)rnd[(size_t)row * 128 + 64 + lane];
    double rs = r0 * r0 + r1 * r1;
    #pragma unroll
    for (int off = 32; off > 0; off >>= 1) rs += __shfl_xor(rs, off, 64);
    double ratio = sqrt(bestv) / sqrt(rs) + 1e-12;
    quant[(size_t)row * 128 + lane]      = (float)(x0 + ratio * r0);
    quant[(size_t)row * 128 + 64 + lane] = (float)(x1 + ratio * r1);
    if (lane == 0) {
        out_mi[row] = (float)bestk;
        atomicAdd(counts + bestk, 1);
    }
}

// ---------------------------------------------------------------------------
// k_perplex: perplexity + new_used (single block)
__global__ __launch_bounds__(256) void k_perplex(
    const int* __restrict__ counts, const int* __restrict__ used_in,
    float* __restrict__ out_used, float* __restrict__ out_perp)
{
    __shared__ double red[256];
    int tid = threadIdx.x;
    double e = 0.0;
    for (int k = tid; k < KCB; k += 256) {
        int c = counts[k];
        out_used[k] = (float)(used_in[k] + c);
        if (c > 0) {
            double p = (double)c / 8192.0;
            e += p * log(p + 1e-12);
        }
    }
    red[tid] = e;
    __syncthreads();
    for (int s = 128; s > 0; s >>= 1) {
        if (tid < s) red[tid] += red[tid + s];
        __syncthreads();
    }
    if (tid == 0) out_perp[0] = (float)exp(-red[0]);
}

// ---------------------------------------------------------------------------
// k_decode: out[b,s2,m] = sum_d2 quant[b*8192 + d2*64 + s2] * W_out[d2,m] + b_out[m]
__global__ __launch_bounds__(256) void k_decode(
    const float* __restrict__ quant, const float* __restrict__ W_out,
    const float* __restrict__ b_out, float* __restrict__ out)
{
    __shared__ float As[8192];             // [d2][s2] (raw reinterpretation!)
    __shared__ float Bs[8192];             // [d2][64 m]
    const int tid = threadIdx.x;
    const int m0  = blockIdx.x * 64;
    const int b   = blockIdx.y;
    #pragma unroll
    for (int it = 0; it < 8; ++it) {
        int flat = it * 1024 + tid * 4;
        *(float4*)&As[flat] = *(const float4*)(quant + (size_t)b * 8192 + flat);
        int d2 = flat >> 6, m = flat & 63;
        *(float4*)&Bs[flat] = *(const float4*)(W_out + (size_t)d2 * 512 + m0 + m);
    }
    __syncthreads();
    const int tx = tid & 15, ty = tid >> 4;
    float acc[4][4];
    #pragma unroll
    for (int i = 0; i < 4; ++i)
        #pragma unroll
        for (int j = 0; j < 4; ++j) acc[i][j] = 0.f;
    #pragma unroll 8
    for (int d2 = 0; d2 < 128; ++d2) {
        float4 a  = *(const float4*)&As[d2 * 64 + ty * 4];
        float4 b4 = *(const float4*)&Bs[d2 * 64 + tx * 4];
        float av[4] = {a.x, a.y, a.z, a.w};
        float bv[4] = {b4.x, b4.y, b4.z, b4.w};
        #pragma unroll
        for (int i = 0; i < 4; ++i)
            #pragma unroll
            for (int j = 0; j < 4; ++j)
                acc[i][j] = fmaf(av[i], bv[j], acc[i][j]);
    }
    float4 bo = *(const float4*)(b_out + m0 + tx * 4);
    float bob[4] = {bo.x, bo.y, bo.z, bo.w};
    #pragma unroll
    for (int i = 0; i < 4; ++i) {
        int s2 = ty * 4 + i;
        float4 o;
        o.x = acc[i][0] + bob[0];
        o.y = acc[i][1] + bob[1];
        o.z = acc[i][2] + bob[2];
        o.w = acc[i][3] + bob[3];
        *(float4*)(out + (size_t)b * 32768 + (size_t)s2 * 512 + m0 + tx * 4) = o;
    }
}

// ---------------------------------------------------------------------------
extern "C" void kernel_launch(void* const* d_in, const int* in_sizes, int n_in,
                              void* d_out, int out_size, void* d_ws, size_t ws_size,
                              hipStream_t stream) {
    const float* first  = (const float*)d_in[0];
    const float* last   = (const float*)d_in[1];
    const float* rnd    = (const float*)d_in[2];
    const float* cb     = (const float*)d_in[3];
    const float* W_in   = (const float*)d_in[4];
    const float* conv_w = (const float*)d_in[6];
    const float* W_out  = (const float*)d_in[8];
    const float* b_out  = (const float*)d_in[9];
    const int*   used   = (const int*)d_in[10];

    float* out      = (float*)d_out;
    float* out_perp = out + 4194304;               // B*64*DIM
    float* out_used = out + 4194305;
    float* out_mi   = out + 4194305 + 16384;

    char* ws = (char*)d_ws;
    double*         H      = (double*)(ws);                 // 33,554,432 B
    double*         X      = (double*)(ws + 33554432);      //  8,388,608 B
    unsigned short* Cbb    = (unsigned short*)(ws + 41943040); // 4,194,304 B
    float*          W2     = (float*) (ws + 46137344);      //    589,824 B
    float*          c2f    = (float*) (ws + 46727168);      //     65,536 B
    int*            cand   = (int*)   (ws + 46792704);      //    524,288 B
    float*          quant  = (float*) (ws + 47316992);      //  4,194,304 B
    int*            counts = (int*)   (ws + 51511296);      //     65,536 B
    unsigned short* Xb     = (unsigned short*)(ws + 51576832); // 2,097,152 B
                                                            // total 53,673,984 B

    hipMemsetAsync(counts, 0, KCB * sizeof(int), stream);
    k_wt<<<576, 256, 0, stream>>>(conv_w, W2);
    k_c2<<<64, 256, 0, stream>>>(cb, c2f);
    k_cbbf<<<2048, 256, 0, stream>>>(cb, Cbb);
    k_encode_gemm<<<2048, 256, 0, stream>>>(last, first, W_in, H);
    k_conv<<<512, 256, 0, stream>>>(H, W2, X, Xb);
    k_dist_mfma<<<dim3(64, 8), 256, 0, stream>>>(Xb, Cbb, c2f, cand);
    k_refine<<<2048, 256, 0, stream>>>(X, cb, cand, rnd, counts, quant, out_mi);
    k_perplex<<<1, 256, 0, stream>>>(counts, used, out_used, out_perp);
    k_decode<<<dim3(8, 128), 256, 0, stream>>>(quant, W_out, b_out, out);
}

// Round 8
// 434.494 us; speedup vs baseline: 1.0166x; 1.0166x over previous
//
#include <hip/hip_runtime.h>
#include <math.h>

// Problem constants
//   B=128, S=256, DIM=512, D=128, K=16384, grid 16x16 -> conv out 8x8 -> N=B*64=8192
#define NROWS 8192
#define KCB   16384

using frag_ab = __attribute__((ext_vector_type(8))) short;   // 8 bf16 (4 VGPR)
using frag_cd = __attribute__((ext_vector_type(4))) float;   // 4 fp32 acc
using f32x4   = __attribute__((ext_vector_type(4))) float;
using f64x4   = __attribute__((ext_vector_type(4))) double;  // fp64 MFMA acc

__device__ inline unsigned short f2bf(float f) {             // RNE f32->bf16
    unsigned u = __float_as_uint(f);
    return (unsigned short)((u + 0x7FFFu + ((u >> 16) & 1u)) >> 16);
}

// Layout self-probe for v_mfma_f64_16x16x4 (HW-validated in round 3):
// decodes per-lane/slot (m,n) of the D fragment; returns ok.
__device__ inline int mfma_f64_probe(int pm[4], int pn[4], int kq) {
    f64x4 z; z[0] = 0.0; z[1] = 0.0; z[2] = 0.0; z[3] = 0.0;
    const double dl = (double)(threadIdx.x & 63);
    f64x4 d1 = __builtin_amdgcn_mfma_f64_16x16x4f64(dl, 1.0, z, 0, 0, 0);
    f64x4 d2 = __builtin_amdgcn_mfma_f64_16x16x4f64(1.0, dl, z, 0, 0, 0);
    const double pk = (double)(1 << (4 * kq));         // 16^kq
    f64x4 d3 = __builtin_amdgcn_mfma_f64_16x16x4f64(pk, dl, z, 0, 0, 0);
    int okl = 1;
    #pragma unroll
    for (int s = 0; s < 4; ++s) {
        double v1 = d1[s] - 96.0, v2 = d2[s] - 96.0;
        int i1 = (int)v1, i2 = (int)v2;
        okl &= (d1[s] == (double)(96 + i1)) & (i1 >= 0) & (i1 < 64) & ((i1 & 3) == 0);
        okl &= (d2[s] == (double)(96 + i2)) & (i2 >= 0) & (i2 < 64) & ((i2 & 3) == 0);
        pm[s] = i1 >> 2;
        pn[s] = i2 >> 2;
        okl &= (d3[s] == 4369.0 * (double)pn[s] + 205056.0);
    }
    return __all(okl);
}

// ---------------------------------------------------------------------------
// k_wt: transpose conv_w [co][ci][kh][kw] -> W2 [(kh*3+kw)][ci][co]  (f32)
__global__ __launch_bounds__(256) void k_wt(const float* __restrict__ cw,
                                            float* __restrict__ W2) {
    int gid = blockIdx.x * 256 + threadIdx.x;     // 147456 total
    if (gid >= 147456) return;
    int co = gid & 127;
    int ci = (gid >> 7) & 127;
    int kk = gid >> 14;                           // 0..8
    W2[gid] = cw[(size_t)co * 1152 + ci * 9 + kk];
}

// ---------------------------------------------------------------------------
// k_c2: c2f[k] = sum_d cb[k][d]^2 + 1024  (bias keeps k_dist scores positive
// so raw float bits are a monotone sort key; k_refine never reads c2f)
__global__ __launch_bounds__(256) void k_c2(const float* __restrict__ cb,
                                            float* __restrict__ c2f) {
    int k = blockIdx.x * 256 + threadIdx.x;
    const float* row = cb + (size_t)k * 128;
    double s = 0.0;
    #pragma unroll
    for (int d = 0; d < 128; d += 4) {
        float4 v = *(const float4*)(row + d);
        s += (double)v.x * v.x + (double)v.y * v.y
           + (double)v.z * v.z + (double)v.w * v.w;
    }
    c2f[k] = (float)s + 1024.0f;
}

// ---------------------------------------------------------------------------
// k_cbbf: convert codebook f32 -> bf16 rows [16384][128]
__global__ __launch_bounds__(256) void k_cbbf(const float* __restrict__ cb,
                                              unsigned short* __restrict__ Cbb) {
    int gid = blockIdx.x * 256 + threadIdx.x;     // x4 elements, 524288 total
    float4 v = ((const float4*)cb)[gid];
    ushort4 o;
    o.x = f2bf(v.x); o.y = f2bf(v.y); o.z = f2bf(v.z); o.w = f2bf(v.w);
    ((ushort4*)Cbb)[gid] = o;
}

// ---------------------------------------------------------------------------
// k_encode_gemm: H = (last - first) @ W_in, fp64 via v_mfma_f64_16x16x4.
// M=32768, N=128, K=512. Round-8: back to the R5 shape (BM=32, BK=64,
// grid 1024, 4 blocks/CU = best measured 102 us), plus the latency fix the
// R6/R7 data points to: occupancy 33% and 61% both gave ~50-53% MfmaUtil,
// so the stall is per-wave load->MFMA serialization, not wave count.
// Fix: hoist ALL 32 W_in loads of a K-step into registers (fully unrolled
// preload loop, static indices) BEFORE the MFMA chain -- loads pipeline in
// the memory system with the whole step (~1000 cy) to return; the MFMA loop
// then only waits on ds_reads. MFMA operand sequence byte-identical to R5
// -> bit-identical H. Probe + scalar fallback as before.
__global__ __launch_bounds__(256, 4) void k_encode_gemm(
    const float* __restrict__ last, const float* __restrict__ first,
    const float* __restrict__ W_in, double* __restrict__ H)
{
    __shared__ double As[64][33];    // [k][row] 16.9 KiB (pad 32->33)
    const int tid  = threadIdx.x;
    const int lane = tid & 63;
    const int w    = tid >> 6;
    const int row0 = blockIdx.x * 32;
    const int wn   = w * 32;
    const int lm   = lane & 15;
    const int kq   = lane >> 4;

    int pm[4], pn[4];
    const int ok = mfma_f64_probe(pm, pn, kq);
    if (!ok) {
        #pragma unroll
        for (int s = 0; s < 4; ++s) { pm[s] = 4 * kq + s; pn[s] = lm; }
    }

    f64x4 acc[2][2];
    #pragma unroll
    for (int i = 0; i < 2; ++i)
        #pragma unroll
        for (int j = 0; j < 2; ++j)
            #pragma unroll
            for (int q = 0; q < 4; ++q) acc[i][j][q] = 0.0;

    const int srow = tid >> 3;           // A-stage: row 0..31
    const int skb  = (tid & 7) * 8;      // A-stage: k base 0,8,...,56
    const float* lp0 = last  + (size_t)(row0 + srow) * 512 + skb;
    const float* fp0 = first + (size_t)(row0 + srow) * 512 + skb;
    const float* wbase = W_in + wn + lm; // lane's B column base

    for (int k0 = 0; k0 < 512; k0 += 64) {
        if (k0) __syncthreads();
        {   // stage A-diff (f64, transposed): 32 rows x 64 k
            const float4 l0 = *(const float4*)(lp0 + k0);
            const float4 l1 = *(const float4*)(lp0 + k0 + 4);
            const float4 f0 = *(const float4*)(fp0 + k0);
            const float4 f1 = *(const float4*)(fp0 + k0 + 4);
            As[skb + 0][srow] = (double)l0.x - (double)f0.x;
            As[skb + 1][srow] = (double)l0.y - (double)f0.y;
            As[skb + 2][srow] = (double)l0.z - (double)f0.z;
            As[skb + 3][srow] = (double)l0.w - (double)f0.w;
            As[skb + 4][srow] = (double)l1.x - (double)f1.x;
            As[skb + 5][srow] = (double)l1.y - (double)f1.y;
            As[skb + 6][srow] = (double)l1.z - (double)f1.z;
            As[skb + 7][srow] = (double)l1.w - (double)f1.w;
        }
        __syncthreads();
        if (ok) {
            // preload ALL B f32 for this K-step (static idx -> registers)
            float bf[32];
            #pragma unroll
            for (int kc = 0; kc < 16; ++kc) {
                const float* wp = wbase + (size_t)(k0 + kc * 4 + kq) * 128;
                bf[2 * kc]     = wp[0];
                bf[2 * kc + 1] = wp[16];
            }
            #pragma unroll
            for (int kc = 0; kc < 16; ++kc) {
                const int kk = kc * 4 + kq;
                double a0 = As[kk][lm];
                double a1 = As[kk][16 + lm];
                double b0 = (double)bf[2 * kc];
                double b1 = (double)bf[2 * kc + 1];
                acc[0][0] = __builtin_amdgcn_mfma_f64_16x16x4f64(a0, b0, acc[0][0], 0, 0, 0);
                acc[0][1] = __builtin_amdgcn_mfma_f64_16x16x4f64(a0, b1, acc[0][1], 0, 0, 0);
                acc[1][0] = __builtin_amdgcn_mfma_f64_16x16x4f64(a1, b0, acc[1][0], 0, 0, 0);
                acc[1][1] = __builtin_amdgcn_mfma_f64_16x16x4f64(a1, b1, acc[1][1], 0, 0, 0);
            }
        } else {
            #pragma unroll 4
            for (int k = 0; k < 64; ++k) {
                double b0 = (double)W_in[(size_t)(k0 + k) * 128 + wn + lm];
                double b1 = (double)W_in[(size_t)(k0 + k) * 128 + wn + 16 + lm];
                #pragma unroll
                for (int i = 0; i < 2; ++i) {
                    const double* ap = &As[k][16 * i + 4 * kq];
                    #pragma unroll
                    for (int s = 0; s < 4; ++s) {
                        double a = ap[s];
                        acc[i][0][s] = fma(a, b0, acc[i][0][s]);
                        acc[i][1][s] = fma(a, b1, acc[i][1][s]);
                    }
                }
            }
        }
    }
    #pragma unroll
    for (int i = 0; i < 2; ++i)
        #pragma unroll
        for (int j = 0; j < 2; ++j)
            #pragma unroll
            for (int s = 0; s < 4; ++s)
                H[(size_t)(row0 + 16 * i + pm[s]) * 128 + wn + 16 * j + pn[s]]
                    = acc[i][j][s];
}

// ---------------------------------------------------------------------------
// k_conv: 3x3 stride-2 pad-1 conv (no bias; cancels), fp64 via MFMA.
// im2col GEMM: M=8192 out rows, N=128 co, K=9 taps x 128 ci.
// Block = 16 rows (batch b, oh pair {2j,2j+1}); input slice ih in
// [4j-1, 4j+3] -> Hs[5][16][128] f64 = 80 KiB exactly -> 2 blocks/CU.
// 4 waves x 32 co: per wave 1 m-frag x 2 n-frags; A from LDS (OOB taps
// masked by 0/1 multiplier), B = W2 f32 direct from L1/L2 + cvt.
// K-order tap-major (reassociation vs ci-major baseline: fp64 ulp, safe).
// Same probe + scalar fallback as encode.
__global__ __launch_bounds__(256) void k_conv(
    const double* __restrict__ H, const float* __restrict__ W2,
    double* __restrict__ X, unsigned short* __restrict__ Xb)
{
    __shared__ double Hs[5 * 2048];          // [ihr][iw][ci]  80 KiB exact
    const int tid  = threadIdx.x;
    const int lane = tid & 63;
    const int w    = tid >> 6;
    const int n0   = blockIdx.x * 16;        // 16 output rows
    const int b    = blockIdx.x >> 2;
    const int j    = blockIdx.x & 3;         // oh in {2j, 2j+1}
    const int ihbase = 4 * j - 1;
    const int wn   = w * 32;
    const int lm   = lane & 15;
    const int kq   = lane >> 4;

    int pm[4], pn[4];
    const int ok = mfma_f64_probe(pm, pn, kq);

    // stage 5 H rows (zero-fill ih=-1 for j==0)
    #pragma unroll
    for (int it = 0; it < 20; ++it) {
        int slot = it * 256 + tid;           // 5120 double2 slots
        int r = slot >> 10;                  // 0..4
        int rem = (slot & 1023) * 2;         // f64 offset within row
        int ih = ihbase + r;
        double2 v = (ih >= 0)
            ? *(const double2*)(H + (size_t)b * 32768 + (size_t)ih * 2048 + rem)
            : make_double2(0.0, 0.0);
        *(double2*)&Hs[r * 2048 + rem] = v;
    }
    __syncthreads();

    if (ok) {
        f64x4 acc0, acc1;
        #pragma unroll
        for (int q = 0; q < 4; ++q) { acc0[q] = 0.0; acc1[q] = 0.0; }
        const int ow = lm & 7, ohl = lm >> 3;
        #pragma unroll
        for (int kh = 0; kh < 3; ++kh) {
            #pragma unroll
            for (int kw = 0; kw < 3; ++kw) {
                const int tap = kh * 3 + kw;
                const int iw  = 2 * ow - 1 + kw;
                const int ihr = 2 * ohl + kh;
                const int valid = (iw >= 0) & (ihbase + ihr >= 0);
                const int aoff = valid ? (ihr * 2048 + iw * 128 + kq) : 0;
                const double msk = valid ? 1.0 : 0.0;
                const float* wbase = W2 + (size_t)(tap * 128 + kq) * 128 + wn + lm;
                #pragma unroll 4
                for (int ci0 = 0; ci0 < 128; ci0 += 4) {
                    double a  = Hs[aoff + ci0] * msk;
                    double b0 = (double)wbase[ci0 * 128];
                    double b1 = (double)wbase[ci0 * 128 + 16];
                    acc0 = __builtin_amdgcn_mfma_f64_16x16x4f64(a, b0, acc0, 0, 0, 0);
                    acc1 = __builtin_amdgcn_mfma_f64_16x16x4f64(a, b1, acc1, 0, 0, 0);
                }
            }
        }
        #pragma unroll
        for (int s = 0; s < 4; ++s) {
            size_t n = n0 + pm[s];
            int c0 = wn + pn[s];
            X [n * 128 + c0]      = acc0[s];
            Xb[n * 128 + c0]      = f2bf((float)acc0[s]);
            X [n * 128 + c0 + 16] = acc1[s];
            Xb[n * 128 + c0 + 16] = f2bf((float)acc1[s]);
        }
    } else {
        // scalar fallback (never runs on validated HW): 8 outputs/thread
        const int co   = wn + (lane & 31);
        const int half = lane >> 5;
        double facc[8];
        #pragma unroll
        for (int i = 0; i < 8; ++i) facc[i] = 0.0;
        for (int ci = 0; ci < 128; ++ci) {
            #pragma unroll
            for (int kh = 0; kh < 3; ++kh) {
                #pragma unroll
                for (int kw = 0; kw < 3; ++kw) {
                    double wv = (double)W2[(size_t)((kh * 3 + kw) * 128 + ci) * 128 + co];
                    #pragma unroll
                    for (int i = 0; i < 8; ++i) {
                        int m = half * 8 + i;
                        int iw = 2 * (m & 7) - 1 + kw;
                        int ihr = 2 * (m >> 3) + kh;
                        double hv = (iw >= 0 && ihbase + ihr >= 0)
                                  ? Hs[ihr * 2048 + iw * 128 + ci] : 0.0;
                        facc[i] = fma(hv, wv, facc[i]);
                    }
                }
            }
        }
        #pragma unroll
        for (int i = 0; i < 8; ++i) {
            size_t n = n0 + half * 8 + i;
            X [n * 128 + co] = facc[i];
            Xb[n * 128 + co] = f2bf((float)facc[i]);
        }
    }
}

// ---------------------------------------------------------------------------
// k_dist_mfma: bf16 MFMA candidate sweep. Block = 128 rows x 2048-code split;
// grid (64, 8) = 512 blocks (2/CU). Per chunk of 128 codes: 16x16x32 MFMA,
// codes as M, rows as N (D: col=lane&15=row, row=quad*4+reg=code).
// LDS exactly 64 KiB; 16B chunks XOR-swizzled (ch ^= row&15) -> conflict-free.
// Selection: score u = (||c||^2+1024) - 2 x.c > 0; sortable uint key =
// (bits(u) & ~0x7FF) | split-local code idx (11 bits); top-2 per (lane,row)
// class via min/max (no cndmask), then per-row top-2 of 16 via LDS.
// Coverage: bf16 noise sigma~0.05 + trunc <0.5 vs rank gaps ~7-20 -> safe;
// fp64 k_refine picks the exact argmin among the 16 candidates.
__global__ __launch_bounds__(256) void k_dist_mfma(
    const unsigned short* __restrict__ Xb, const unsigned short* __restrict__ Cbb,
    const float* __restrict__ c2f, int* __restrict__ cand)
{
    __shared__ __align__(16) unsigned short Xs[128 * 128];   // 32 KiB
    __shared__ __align__(16) unsigned short Cs[128 * 128];   // 32 KiB
    const int tid   = threadIdx.x;
    const int row0  = blockIdx.x * 128;
    const int split = blockIdx.y;
    const int lane  = tid & 63;
    const int w     = tid >> 6;
    const int quad  = lane >> 4;
    const int lm    = lane & 15;
    const int cw    = (w & 1) * 64;       // wave's code sub-tile
    const int rw    = (w >> 1) * 64;      // wave's row sub-tile

    #pragma unroll
    for (int it = 0; it < 8; ++it) {      // stage X tile once (swizzled)
        int flat = it * 256 + tid;
        int r = flat >> 4, ch = flat & 15;
        *(uint4*)&Xs[r * 128 + (((ch ^ r) & 15) << 3) + (ch & 16 ? 0 : 0)] =
            *(const uint4*)(Xb + (size_t)(row0 + r) * 128 + ch * 8);
    }

    unsigned k1[4], k2[4];
    #pragma unroll
    for (int j = 0; j < 4; ++j) { k1[j] = 0xFFFFFFFFu; k2[j] = 0xFFFFFFFFu; }

    for (int chunk = 0; chunk < 16; ++chunk) {
        const int kb = split * 2048 + chunk * 128;
        if (chunk) __syncthreads();
        #pragma unroll
        for (int it = 0; it < 8; ++it) {  // stage code chunk (swizzled)
            int flat = it * 256 + tid;
            int r = flat >> 4, ch = flat & 15;
            *(uint4*)&Cs[r * 128 + ((ch ^ (r & 15)) << 3)] =
                *(const uint4*)(Cbb + (size_t)(kb + r) * 128 + ch * 8);
        }
        __syncthreads();

        frag_cd acc[4][4];
        #pragma unroll
        for (int i = 0; i < 4; ++i)
            #pragma unroll
            for (int j = 0; j < 4; ++j)
                #pragma unroll
                for (int r = 0; r < 4; ++r) acc[i][j][r] = 0.f;

        #pragma unroll
        for (int kk = 0; kk < 4; ++kk) {
            const int chs = ((kk * 4 + quad) ^ lm) << 3;
            frag_ab a[4], b[4];
            #pragma unroll
            for (int i = 0; i < 4; ++i)
                a[i] = *(const frag_ab*)&Cs[(cw + i * 16 + lm) * 128 + chs];
            #pragma unroll
            for (int j = 0; j < 4; ++j)
                b[j] = *(const frag_ab*)&Xs[(rw + j * 16 + lm) * 128 + chs];
            #pragma unroll
            for (int i = 0; i < 4; ++i)
                #pragma unroll
                for (int j = 0; j < 4; ++j)
                    acc[i][j] = __builtin_amdgcn_mfma_f32_16x16x32_bf16(
                        a[i], b[j], acc[i][j], 0, 0, 0);
        }

        const int ib = chunk * 128 + cw + quad * 4;   // split-local idx base
        #pragma unroll
        for (int i = 0; i < 4; ++i) {
            f32x4 c2v = *(const f32x4*)(c2f + kb + cw + i * 16 + quad * 4);
            #pragma unroll
            for (int j = 0; j < 4; ++j) {
                #pragma unroll
                for (int r = 0; r < 4; ++r) {
                    float u = fmaf(-2.f, acc[i][j][r], c2v[r]);
                    unsigned key = (__float_as_uint(u) & 0xFFFFF800u)
                                 | (unsigned)(ib + i * 16 + r);
                    unsigned nk1 = min(key, k1[j]);
                    k2[j] = min(max(key, k1[j]), k2[j]);
                    k1[j] = nk1;
                }
            }
        }
    }

    // per-row reduce: 8 slots x 2 keys -> top-2 of the split
    __syncthreads();
    uint2* kred = (uint2*)Cs;             // [128 rows][8 slots]
    #pragma unroll
    for (int j = 0; j < 4; ++j)
        kred[(rw + j * 16 + lm) * 8 + (w & 1) * 4 + quad] = make_uint2(k1[j], k2[j]);
    __syncthreads();
    if (tid < 128) {
        unsigned b1 = 0xFFFFFFFFu, b2 = 0xFFFFFFFFu;
        for (int e = 0; e < 8; ++e) {
            uint2 kv = kred[tid * 8 + e];
            unsigned n1 = min(kv.x, b1); b2 = min(max(kv.x, b1), b2); b1 = n1;
            n1 = min(kv.y, b1);          b2 = min(max(kv.y, b1), b2); b1 = n1;
        }
        int base = split * 2048;
        int* o = cand + (size_t)(row0 + tid) * 16 + split * 2;
        o[0] = base + (int)(b1 & 0x7FFu);
        o[1] = base + (int)(b2 & 0x7FFu);
    }
}

// ---------------------------------------------------------------------------
// k_refine: fp64-exact argmin over 16 candidates; quantize; counts; indices.
__global__ __launch_bounds__(256) void k_refine(
    const double* __restrict__ X, const float* __restrict__ cb,
    const int* __restrict__ cand, const float* __restrict__ rnd,
    int* __restrict__ counts, float* __restrict__ quant,
    float* __restrict__ out_mi)
{
    const int wid  = threadIdx.x >> 6;
    const int lane = threadIdx.x & 63;
    const int row  = blockIdx.x * 4 + wid;
    const double x0 = X[(size_t)row * 128 + lane];
    const double x1 = X[(size_t)row * 128 + 64 + lane];
    double bestv = 1e300; int bestk = 0;
    for (int c = 0; c < 16; ++c) {
        int k = cand[(size_t)row * 16 + c] & (KCB - 1);   // defensive clamp
        double t0 = x0 - (double)cb[(size_t)k * 128 + lane];
        double t1 = x1 - (double)cb[(size_t)k * 128 + 64 + lane];
        double s = t0 * t0 + t1 * t1;
        #pragma unroll
        for (int off = 32; off > 0; off >>= 1) s += __shfl_xor(s, off, 64);
        if (s < bestv) { bestv = s; bestk = k; }
    }
    double r0 = (double)rnd[(size_t)row * 128 + lane];
    double r1 = (double)rnd[(size_t)row * 128 + 64 + lane];
    double rs = r0 * r0 + r1 * r1;
    #pragma unroll
    for (int off = 32; off > 0; off >>= 1) rs += __shfl_xor(rs, off, 64);
    double ratio = sqrt(bestv) / sqrt(rs) + 1e-12;
    quant[(size_t)row * 128 + lane]      = (float)(x0 + ratio * r0);
    quant[(size_t)row * 128 + 64 + lane] = (float)(x1 + ratio * r1);
    if (lane == 0) {
        out_mi[row] = (float)bestk;
        atomicAdd(counts + bestk, 1);
    }
}

// ---------------------------------------------------------------------------
// k_perplex: perplexity + new_used (single block)
__global__ __launch_bounds__(256) void k_perplex(
    const int* __restrict__ counts, const int* __restrict__ used_in,
    float* __restrict__ out_used, float* __restrict__ out_perp)
{
    __shared__ double red[256];
    int tid = threadIdx.x;
    double e = 0.0;
    for (int k = tid; k < KCB; k += 256) {
        int c = counts[k];
        out_used[k] = (float)(used_in[k] + c);
        if (c > 0) {
            double p = (double)c / 8192.0;
            e += p * log(p + 1e-12);
        }
    }
    red[tid] = e;
    __syncthreads();
    for (int s = 128; s > 0; s >>= 1) {
        if (tid < s) red[tid] += red[tid + s];
        __syncthreads();
    }
    if (tid == 0) out_perp[0] = (float)exp(-red[0]);
}

// ---------------------------------------------------------------------------
// k_decode: out[b,s2,m] = sum_d2 quant[b*8192 + d2*64 + s2] * W_out[d2,m] + b_out[m]
__global__ __launch_bounds__(256) void k_decode(
    const float* __restrict__ quant, const float* __restrict__ W_out,
    const float* __restrict__ b_out, float* __restrict__ out)
{
    __shared__ float As[8192];             // [d2][s2] (raw reinterpretation!)
    __shared__ float Bs[8192];             // [d2][64 m]
    const int tid = threadIdx.x;
    const int m0  = blockIdx.x * 64;
    const int b   = blockIdx.y;
    #pragma unroll
    for (int it = 0; it < 8; ++it) {
        int flat = it * 1024 + tid * 4;
        *(float4*)&As[flat] = *(const float4*)(quant + (size_t)b * 8192 + flat);
        int d2 = flat >> 6, m = flat & 63;
        *(float4*)&Bs[flat] = *(const float4*)(W_out + (size_t)d2 * 512 + m0 + m);
    }
    __syncthreads();
    const int tx = tid & 15, ty = tid >> 4;
    float acc[4][4];
    #pragma unroll
    for (int i = 0; i < 4; ++i)
        #pragma unroll
        for (int j = 0; j < 4; ++j) acc[i][j] = 0.f;
    #pragma unroll 8
    for (int d2 = 0; d2 < 128; ++d2) {
        float4 a  = *(const float4*)&As[d2 * 64 + ty * 4];
        float4 b4 = *(const float4*)&Bs[d2 * 64 + tx * 4];
        float av[4] = {a.x, a.y, a.z, a.w};
        float bv[4] = {b4.x, b4.y, b4.z, b4.w};
        #pragma unroll
        for (int i = 0; i < 4; ++i)
            #pragma unroll
            for (int j = 0; j < 4; ++j)
                acc[i][j] = fmaf(av[i], bv[j], acc[i][j]);
    }
    float4 bo = *(const float4*)(b_out + m0 + tx * 4);
    float bob[4] = {bo.x, bo.y, bo.z, bo.w};
    #pragma unroll
    for (int i = 0; i < 4; ++i) {
        int s2 = ty * 4 + i;
        float4 o;
        o.x = acc[i][0] + bob[0];
        o.y = acc[i][1] + bob[1];
        o.z = acc[i][2] + bob[2];
        o.w = acc[i][3] + bob[3];
        *(float4*)(out + (size_t)b * 32768 + (size_t)s2 * 512 + m0 + tx * 4) = o;
    }
}

// ---------------------------------------------------------------------------
extern "C" void kernel_launch(void* const* d_in, const int* in_sizes, int n_in,
                              void* d_out, int out_size, void* d_ws, size_t ws_size,
                              hipStream_t stream) {
    const float* first  = (const float*)d_in[0];
    const float* last   = (const float*)d_in[1];
    const float* rnd    = (const float*)d_in[2];
    const float* cb     = (const float*)d_in[3];
    const float* W_in   = (const float*)d_in[4];
    const float* conv_w = (const float*)d_in[6];
    const float* W_out  = (const float*)d_in[8];
    const float* b_out  = (const float*)d_in[9];
    const int*   used   = (const int*)d_in[10];

    float* out      = (float*)d_out;
    float* out_perp = out + 4194304;               // B*64*DIM
    float* out_used = out + 4194305;
    float* out_mi   = out + 4194305 + 16384;

    char* ws = (char*)d_ws;
    double*         H      = (double*)(ws);                 // 33,554,432 B
    double*         X      = (double*)(ws + 33554432);      //  8,388,608 B
    unsigned short* Cbb    = (unsigned short*)(ws + 41943040); // 4,194,304 B
    float*          W2     = (float*) (ws + 46137344);      //    589,824 B
    float*          c2f    = (float*) (ws + 46727168);      //     65,536 B
    int*            cand   = (int*)   (ws + 46792704);      //    524,288 B
    float*          quant  = (float*) (ws + 47316992);      //  4,194,304 B
    int*            counts = (int*)   (ws + 51511296);      //     65,536 B
    unsigned short* Xb     = (unsigned short*)(ws + 51576832); // 2,097,152 B
                                                            // total 53,673,984 B

    hipMemsetAsync(counts, 0, KCB * sizeof(int), stream);
    k_wt<<<576, 256, 0, stream>>>(conv_w, W2);
    k_c2<<<64, 256, 0, stream>>>(cb, c2f);
    k_cbbf<<<2048, 256, 0, stream>>>(cb, Cbb);
    k_encode_gemm<<<1024, 256, 0, stream>>>(last, first, W_in, H);
    k_conv<<<512, 256, 0, stream>>>(H, W2, X, Xb);
    k_dist_mfma<<<dim3(64, 8), 256, 0, stream>>>(Xb, Cbb, c2f, cand);
    k_refine<<<2048, 256, 0, stream>>>(X, cb, cand, rnd, counts, quant, out_mi);
    k_perplex<<<1, 256, 0, stream>>>(counts, used, out_used, out_perp);
    k_decode<<<dim3(8, 128), 256, 0, stream>>>(quant, W_out, b_out, out);
}